// Round 8
// baseline (403.201 us; speedup 1.0000x reference)
//
#include <hip/hip_runtime.h>
#include <hip/hip_fp16.h>
#include <stdint.h>

#define IN_DIM   4096
#define OUT_DIM  4096
#define TPB      512
#define TOKS     8        // tokens per block; LDS = 4 f16x2 pairs per column

typedef float  f32x4 __attribute__((ext_vector_type(4)));

// pack two fp32 -> f16x2 dword (lo = a, hi = b) via v_cvt_pkrtz_f16_f32 (1 instr)
__device__ __forceinline__ uint32_t pack_f16x2(float a, float b) {
    auto h = __builtin_amdgcn_cvt_pkrtz(a, b);   // __fp16 ext_vector_type(2)
    uint32_t u;
    __builtin_memcpy(&u, &h, 4);
    return u;
}

// Stage 8 tokens of x (fp32, [token][IN_DIM]) into LDS as f16x2, column-major:
// xs[col*4 + pair]; pair p holds tokens (2p, 2p+1).
// Per-lane write rotation keeps staging writes ~2-way banked (free).
__device__ __forceinline__ void stage_x_tile(const float* __restrict__ x,
                                             size_t tb, uint32_t* xs, int tid) {
    const int lane = tid & 63;
    const int wave = tid >> 6;          // 0..7
    const int tp   = lane >> 4;         // token pair 0..3
    const int rot  = (lane >> 1) & 3;   // write-order rotation
    const float* xa = x + (tb + 2 * (size_t)tp) * IN_DIM;
    const float* xb = xa + IN_DIM;
    #pragma unroll
    for (int it = 0; it < IN_DIM / 4 / 128; ++it) {   // 8 iterations
        const int c4 = (lane & 15) + 16 * wave + 128 * it;   // float4 column group
        const f32x4 a = __builtin_nontemporal_load(
            reinterpret_cast<const f32x4*>(xa + 4 * c4));
        const f32x4 b = __builtin_nontemporal_load(
            reinterpret_cast<const f32x4*>(xb + 4 * c4));
        const uint32_t d0 = pack_f16x2(a[0], b[0]);
        const uint32_t d1 = pack_f16x2(a[1], b[1]);
        const uint32_t d2 = pack_f16x2(a[2], b[2]);
        const uint32_t d3 = pack_f16x2(a[3], b[3]);
        // branchless rotate-left by rot (no runtime array indexing -> no scratch)
        const uint32_t t0 = (rot & 2) ? d2 : d0;
        const uint32_t t1 = (rot & 2) ? d3 : d1;
        const uint32_t t2 = (rot & 2) ? d0 : d2;
        const uint32_t t3 = (rot & 2) ? d1 : d3;
        const uint32_t u0 = (rot & 1) ? t1 : t0;
        const uint32_t u1 = (rot & 1) ? t2 : t1;
        const uint32_t u2 = (rot & 1) ? t3 : t2;
        const uint32_t u3 = (rot & 1) ? t0 : t3;
        const int cb = 4 * c4;
        xs[(cb + ((0 + rot) & 3)) * 4 + tp] = u0;
        xs[(cb + ((1 + rot) & 3)) * 4 + tp] = u1;
        xs[(cb + ((2 + rot) & 3)) * 4 + tp] = u2;
        xs[(cb + ((3 + rot) & 3)) * 4 + tp] = u3;
    }
}

// ELL metadata, group-of-4 interleaved: ell4[g*OUT_DIM + r] = uint4 of entries
// k=4g..4g+3; entry = (bf16(value) << 16) | (col << 4). Zero padded.
// BANK-AWARE SLOT ASSIGNMENT: entries of row r are permuted (sum is
// order-independent) so slot j prefers bank-group (j + r) & 7, where
// group = col & 7 is the LDS bank quartet of the 16B entry. Across any 8
// consecutive lanes (rows) at the same k-step, groups then tile all 8 bank
// quartets -> near-conflict-free ds_read_b128. One thread per row.
__global__ void build_ell(const float* __restrict__ values,
                          const int* __restrict__ row_offs,
                          const int* __restrict__ col_idx,
                          uint4* __restrict__ ell4, int galloc) {
    const int r = blockIdx.x * blockDim.x + threadIdx.x;
    if (r >= OUT_DIM) return;
    const int beg = row_offs[r];
    const int end = row_offs[r + 1];
    int klen = end - beg;
    const int nslot = 4 * galloc;
    if (klen > nslot) klen = nslot;            // safety (never hit: ELL sized from kmax)
    const bool reorder = (klen <= 64);         // used-mask is 64-bit
    uint64_t used = 0;

    for (int g = 0; g < galloc; ++g) {
        uint32_t e0 = 0, e1 = 0, e2 = 0, e3 = 0;
        #pragma unroll
        for (int j4 = 0; j4 < 4; ++j4) {
            const int j = 4 * g + j4;
            uint32_t u = 0;
            if (j < klen) {
                int pick = j;
                if (reorder) {
                    const int t = (j + r) & 7;
                    int best = -1, bestd = 9;
                    for (int i = 0; i < klen; ++i) {
                        if ((used >> i) & 1ull) continue;
                        const int d = ((col_idx[beg + i] & 7) - t) & 7;
                        if (d < bestd) { bestd = d; best = i; if (d == 0) break; }
                    }
                    used |= 1ull << best;
                    pick = best;
                }
                const uint32_t c = (uint32_t)col_idx[beg + pick];
                uint32_t vb = __float_as_uint(values[beg + pick]);
                vb = (vb + 0x7fffu + ((vb >> 16) & 1u)) & 0xffff0000u;
                u = vb | (c << 4);
            }
            if (j4 == 0) e0 = u; else if (j4 == 1) e1 = u;
            else if (j4 == 2) e2 = u; else e3 = u;
        }
        ell4[(size_t)g * OUT_DIM + r] = make_uint4(e0, e1, e2, e3);
    }
}

// 8 MACs from one f16x2-packed uint4 (8 tokens) against value E.
// fmaf((float)f16, f32, f32) folds to v_fma_mix_f32 (no unpack shifts).
#define FMA8(E, D)                                                   \
    do {                                                             \
        const float v_ = __uint_as_float(E);                         \
        const __half2* h_ = reinterpret_cast<const __half2*>(&(D));  \
        acc0 = fmaf(__low2float(h_[0]),  v_, acc0);                  \
        acc1 = fmaf(__high2float(h_[0]), v_, acc1);                  \
        acc2 = fmaf(__low2float(h_[1]),  v_, acc2);                  \
        acc3 = fmaf(__high2float(h_[1]), v_, acc3);                  \
        acc4 = fmaf(__low2float(h_[2]),  v_, acc4);                  \
        acc5 = fmaf(__high2float(h_[2]), v_, acc5);                  \
        acc6 = fmaf(__low2float(h_[3]),  v_, acc6);                  \
        acc7 = fmaf(__high2float(h_[3]), v_, acc7);                  \
    } while (0)

// gather: entry's low bits are already the byte offset (col<<4)
#define GATH(D, E)                                                           \
    (D) = *reinterpret_cast<const uint4*>(reinterpret_cast<const char*>(xs) + \
                                          ((E) & 0xfff0u))

__global__ __launch_bounds__(TPB, 4)
void spmm_ell(const float* __restrict__ x, const uint4* __restrict__ ell4,
              float* __restrict__ y, int ng) {   // ng is ODD
    __shared__ __align__(16) uint32_t xs[IN_DIM * (TOKS / 2)];   // 64 KB
    const int tid  = threadIdx.x;
    const size_t tb = (size_t)blockIdx.x * TOKS;

    stage_x_tile(x, tb, xs, tid);
    __syncthreads();

    #pragma unroll 1
    for (int chunk = 0; chunk < OUT_DIM / TPB; ++chunk) {
        const int r = chunk * TPB + tid;
        float acc0 = 0.f, acc1 = 0.f, acc2 = 0.f, acc3 = 0.f;
        float acc4 = 0.f, acc5 = 0.f, acc6 = 0.f, acc7 = 0.f;
        const uint4* ep = ell4 + r;

        // ---- 2-deep software pipeline over k-groups of 4 ----
        uint4 eA = ep[0];                           // group 0
        uint4 dA0, dA1, dA2, dA3;
        GATH(dA0, eA.x); GATH(dA1, eA.y); GATH(dA2, eA.z); GATH(dA3, eA.w);
        uint4 eB = ep[OUT_DIM];                     // group 1
        uint4 dB0, dB1, dB2, dB3;
        const uint4* epn = ep + 2 * (size_t)OUT_DIM;

        #pragma unroll 1
        for (int g = 0; g + 2 < ng; g += 2) {
            // step g: compute (eA,dA); gather g+1 from eB; prefetch e(g+2)
            const uint4 tA = epn[0];
            GATH(dB0, eB.x); GATH(dB1, eB.y); GATH(dB2, eB.z); GATH(dB3, eB.w);
            FMA8(eA.x, dA0); FMA8(eA.y, dA1); FMA8(eA.z, dA2); FMA8(eA.w, dA3);
            // step g+1: compute (eB,dB); gather g+2 from tA; prefetch e(g+3)
            const uint4 tB = epn[OUT_DIM];
            GATH(dA0, tA.x); GATH(dA1, tA.y); GATH(dA2, tA.z); GATH(dA3, tA.w);
            FMA8(eB.x, dB0); FMA8(eB.y, dB1); FMA8(eB.z, dB2); FMA8(eB.w, dB3);
            eA = tA; eB = tB;
            epn += 2 * (size_t)OUT_DIM;
        }
        // epilogue: last (odd) group already gathered in (eA, dA)
        FMA8(eA.x, dA0); FMA8(eA.y, dA1); FMA8(eA.z, dA2); FMA8(eA.w, dA3);

        __builtin_nontemporal_store(acc0, &y[(tb + 0) * OUT_DIM + r]);
        __builtin_nontemporal_store(acc1, &y[(tb + 1) * OUT_DIM + r]);
        __builtin_nontemporal_store(acc2, &y[(tb + 2) * OUT_DIM + r]);
        __builtin_nontemporal_store(acc3, &y[(tb + 3) * OUT_DIM + r]);
        __builtin_nontemporal_store(acc4, &y[(tb + 4) * OUT_DIM + r]);
        __builtin_nontemporal_store(acc5, &y[(tb + 5) * OUT_DIM + r]);
        __builtin_nontemporal_store(acc6, &y[(tb + 6) * OUT_DIM + r]);
        __builtin_nontemporal_store(acc7, &y[(tb + 7) * OUT_DIM + r]);
    }
}

// Fallback if d_ws too small for ELL: direct CSR (fp32 values, f16 tokens).
__global__ __launch_bounds__(TPB, 4)
void spmm_csr(const float* __restrict__ x, const float* __restrict__ values,
              const int* __restrict__ row_offs, const int* __restrict__ col_idx,
              float* __restrict__ y) {
    __shared__ __align__(16) uint32_t xs[IN_DIM * (TOKS / 2)];
    const int tid  = threadIdx.x;
    const size_t tb = (size_t)blockIdx.x * TOKS;

    stage_x_tile(x, tb, xs, tid);
    __syncthreads();

    #pragma unroll 1
    for (int chunk = 0; chunk < OUT_DIM / TPB; ++chunk) {
        const int r = chunk * TPB + tid;
        float acc0 = 0.f, acc1 = 0.f, acc2 = 0.f, acc3 = 0.f;
        float acc4 = 0.f, acc5 = 0.f, acc6 = 0.f, acc7 = 0.f;
        int k = row_offs[r];
        const int ke = row_offs[r + 1];
        for (; k < ke; ++k) {
            const uint32_t e = __float_as_uint(values[k]);
            const uint32_t off = (uint32_t)col_idx[k] << 4;
            uint4 d;
            GATH(d, off);
            FMA8(e, d);
        }
        y[(tb + 0) * OUT_DIM + r] = acc0;
        y[(tb + 1) * OUT_DIM + r] = acc1;
        y[(tb + 2) * OUT_DIM + r] = acc2;
        y[(tb + 3) * OUT_DIM + r] = acc3;
        y[(tb + 4) * OUT_DIM + r] = acc4;
        y[(tb + 5) * OUT_DIM + r] = acc5;
        y[(tb + 6) * OUT_DIM + r] = acc6;
        y[(tb + 7) * OUT_DIM + r] = acc7;
    }
}

extern "C" void kernel_launch(void* const* d_in, const int* in_sizes, int n_in,
                              void* d_out, int out_size, void* d_ws, size_t ws_size,
                              hipStream_t stream) {
    const float* x        = (const float*)d_in[0];
    const float* values   = (const float*)d_in[1];
    const int*   row_offs = (const int*)d_in[2];
    const int*   col_idx  = (const int*)d_in[3];
    float* y = (float*)d_out;

    const int nnz  = in_sizes[1];
    const int rows = in_sizes[2] - 1;              // 4096
    const int ntok = in_sizes[0] / IN_DIM;         // 8192
    const int kmax = nnz / rows + ((nnz % rows) ? 1 : 0);   // 41

    int ng = (kmax + 3) / 4;                       // k-groups of 4 (11 for kmax=41)
    if (!(ng & 1)) ++ng;                           // pipeline needs ODD ng
    const int galloc = ng + 1;                     // +1 zero group for e-prefetch

    dim3 grid(ntok / TOKS), block(TPB);
    const size_t ell_bytes = (size_t)galloc * OUT_DIM * sizeof(uint4);
    if (ws_size >= ell_bytes) {
        uint4* ell4 = (uint4*)d_ws;
        build_ell<<<dim3((OUT_DIM + 255) / 256), dim3(256), 0, stream>>>(
            values, row_offs, col_idx, ell4, galloc);
        spmm_ell<<<grid, block, 0, stream>>>(x, ell4, y, ng);
    } else {
        spmm_csr<<<grid, block, 0, stream>>>(x, values, row_offs, col_idx, y);
    }
}

// Round 9
// 114.960 us; speedup vs baseline: 3.5073x; 3.5073x over previous
//
#include <hip/hip_runtime.h>
#include <hip/hip_fp16.h>
#include <stdint.h>

#define IN_DIM   4096
#define OUT_DIM  4096
#define TPB      512
#define TOKS     8        // tokens per block; LDS = 4 f16x2 pairs per column
#define BTPB     64       // build_ell threads per block (1 wave)
#define NSLOT    48       // max ELL slots per row handled by reorder

typedef float  f32x4 __attribute__((ext_vector_type(4)));

// pack two fp32 -> f16x2 dword (lo = a, hi = b) via v_cvt_pkrtz_f16_f32 (1 instr)
__device__ __forceinline__ uint32_t pack_f16x2(float a, float b) {
    auto h = __builtin_amdgcn_cvt_pkrtz(a, b);   // __fp16 ext_vector_type(2)
    uint32_t u;
    __builtin_memcpy(&u, &h, 4);
    return u;
}

// Stage 8 tokens of x (fp32, [token][IN_DIM]) into LDS as f16x2, column-major:
// xs[col*4 + pair]; pair p holds tokens (2p, 2p+1).
// Per-lane write rotation keeps staging writes ~2-way banked (free).
__device__ __forceinline__ void stage_x_tile(const float* __restrict__ x,
                                             size_t tb, uint32_t* xs, int tid) {
    const int lane = tid & 63;
    const int wave = tid >> 6;          // 0..7
    const int tp   = lane >> 4;         // token pair 0..3
    const int rot  = (lane >> 1) & 3;   // write-order rotation
    const float* xa = x + (tb + 2 * (size_t)tp) * IN_DIM;
    const float* xb = xa + IN_DIM;
    #pragma unroll
    for (int it = 0; it < IN_DIM / 4 / 128; ++it) {   // 8 iterations
        const int c4 = (lane & 15) + 16 * wave + 128 * it;   // float4 column group
        const f32x4 a = __builtin_nontemporal_load(
            reinterpret_cast<const f32x4*>(xa + 4 * c4));
        const f32x4 b = __builtin_nontemporal_load(
            reinterpret_cast<const f32x4*>(xb + 4 * c4));
        const uint32_t d0 = pack_f16x2(a[0], b[0]);
        const uint32_t d1 = pack_f16x2(a[1], b[1]);
        const uint32_t d2 = pack_f16x2(a[2], b[2]);
        const uint32_t d3 = pack_f16x2(a[3], b[3]);
        // branchless rotate-left by rot (no runtime array indexing -> no scratch)
        const uint32_t t0 = (rot & 2) ? d2 : d0;
        const uint32_t t1 = (rot & 2) ? d3 : d1;
        const uint32_t t2 = (rot & 2) ? d0 : d2;
        const uint32_t t3 = (rot & 2) ? d1 : d3;
        const uint32_t u0 = (rot & 1) ? t1 : t0;
        const uint32_t u1 = (rot & 1) ? t2 : t1;
        const uint32_t u2 = (rot & 1) ? t3 : t2;
        const uint32_t u3 = (rot & 1) ? t0 : t3;
        const int cb = 4 * c4;
        xs[(cb + ((0 + rot) & 3)) * 4 + tp] = u0;
        xs[(cb + ((1 + rot) & 3)) * 4 + tp] = u1;
        xs[(cb + ((2 + rot) & 3)) * 4 + tp] = u2;
        xs[(cb + ((3 + rot) & 3)) * 4 + tp] = u3;
    }
}

// ELL metadata, group-of-4 interleaved: ell4[g*OUT_DIM + r] = uint4 of entries
// k=4g..4g+3; entry = (bf16(value) << 16) | (col << 4). Zero padded.
// BANK-AWARE SLOT ASSIGNMENT (O(k) counting-sort version): entries of row r
// are permuted so slot j prefers LDS bank-quartet (j + r) & 7 (quartet of a
// 16B entry = col & 7); across 8 consecutive lanes at the same k-step the
// quartets then tile all 8 -> near-conflict-free ds_read_b128.
// One thread per row; per-row scratch lives in LDS (lane-interleaved).
__global__ __launch_bounds__(BTPB, 1)
void build_ell(const float* __restrict__ values,
               const int* __restrict__ row_offs,
               const int* __restrict__ col_idx,
               uint4* __restrict__ ell4, int galloc) {
    __shared__ uint32_t lA[NSLOT * BTPB];   // unsorted packed entries, 12 KB
    __shared__ uint32_t lB[NSLOT * BTPB];   // group-sorted packed entries, 12 KB
    const int tid = threadIdx.x;
    const int r = blockIdx.x * BTPB + tid;
    if (r >= OUT_DIM) return;
    const int beg = row_offs[r];
    const int end = row_offs[r + 1];
    int klen = end - beg;
    const int nslot = 4 * galloc > NSLOT ? NSLOT : 4 * galloc;
    if (klen > nslot) klen = nslot;   // safety (never hit: ELL sized from kmax)

    // pass 1: load + pack entries into lA; count per-group in cnt64 byte-fields
    uint64_t cnt64 = 0;
    for (int i = 0; i < klen; ++i) {
        const uint32_t c = (uint32_t)col_idx[beg + i];
        uint32_t vb = __float_as_uint(values[beg + i]);
        vb = (vb + 0x7fffu + ((vb >> 16) & 1u)) & 0xffff0000u;
        lA[i * BTPB + tid] = vb | (c << 4);
        cnt64 += 1ull << (8 * (c & 7));
    }

    // pass 2: byte-field exclusive prefix sum -> off64; non-empty-group mask
    uint64_t off64 = 0;
    uint32_t mask = 0, run = 0;
    #pragma unroll
    for (int b = 0; b < 8; ++b) {
        off64 |= (uint64_t)run << (8 * b);
        const uint32_t cb = (uint32_t)(cnt64 >> (8 * b)) & 0xff;
        if (cb) mask |= 1u << b;
        run += cb;
    }

    // pass 3: stable counting sort by group into lB
    uint64_t cur64 = off64;
    for (int i = 0; i < klen; ++i) {
        const uint32_t u = lA[i * BTPB + tid];
        const int g = (u >> 4) & 7;
        const uint32_t pos = (uint32_t)(cur64 >> (8 * g)) & 0xff;
        cur64 += 1ull << (8 * g);
        lB[pos * BTPB + tid] = u;
    }

    // pass 4: emit slots; slot j takes first non-empty group clockwise from (j+r)&7
    uint64_t head64 = off64;
    uint64_t rem64  = cnt64;
    for (int g = 0; g < galloc; ++g) {
        uint32_t e0 = 0, e1 = 0, e2 = 0, e3 = 0;
        #pragma unroll
        for (int j4 = 0; j4 < 4; ++j4) {
            const int j = 4 * g + j4;
            uint32_t u = 0;
            if (j < klen) {
                const int t = (j + r) & 7;
                const uint32_t m2 = ((mask >> t) | (mask << (8 - t))) & 0xff;
                const int b = (t + __builtin_ctz(m2)) & 7;
                const uint32_t hb = (uint32_t)(head64 >> (8 * b)) & 0xff;
                u = lB[hb * BTPB + tid];
                head64 += 1ull << (8 * b);
                rem64  -= 1ull << (8 * b);
                if (!((rem64 >> (8 * b)) & 0xff)) mask &= ~(1u << b);
            }
            if (j4 == 0) e0 = u; else if (j4 == 1) e1 = u;
            else if (j4 == 2) e2 = u; else e3 = u;
        }
        ell4[(size_t)g * OUT_DIM + r] = make_uint4(e0, e1, e2, e3);
    }
}

// 8 MACs from one f16x2-packed uint4 (8 tokens) against value E.
// fmaf((float)f16, f32, f32) folds to v_fma_mix_f32 (no unpack shifts).
#define FMA8(E, D)                                                   \
    do {                                                             \
        const float v_ = __uint_as_float(E);                         \
        const __half2* h_ = reinterpret_cast<const __half2*>(&(D));  \
        acc0 = fmaf(__low2float(h_[0]),  v_, acc0);                  \
        acc1 = fmaf(__high2float(h_[0]), v_, acc1);                  \
        acc2 = fmaf(__low2float(h_[1]),  v_, acc2);                  \
        acc3 = fmaf(__high2float(h_[1]), v_, acc3);                  \
        acc4 = fmaf(__low2float(h_[2]),  v_, acc4);                  \
        acc5 = fmaf(__high2float(h_[2]), v_, acc5);                  \
        acc6 = fmaf(__low2float(h_[3]),  v_, acc6);                  \
        acc7 = fmaf(__high2float(h_[3]), v_, acc7);                  \
    } while (0)

// gather: entry's low bits are already the byte offset (col<<4)
#define GATH(D, E)                                                           \
    (D) = *reinterpret_cast<const uint4*>(reinterpret_cast<const char*>(xs) + \
                                          ((E) & 0xfff0u))

__global__ __launch_bounds__(TPB, 4)
void spmm_ell(const float* __restrict__ x, const uint4* __restrict__ ell4,
              float* __restrict__ y, int ng) {   // ng is ODD
    __shared__ __align__(16) uint32_t xs[IN_DIM * (TOKS / 2)];   // 64 KB
    const int tid  = threadIdx.x;
    const size_t tb = (size_t)blockIdx.x * TOKS;

    stage_x_tile(x, tb, xs, tid);
    __syncthreads();

    #pragma unroll 1
    for (int chunk = 0; chunk < OUT_DIM / TPB; ++chunk) {
        const int r = chunk * TPB + tid;
        float acc0 = 0.f, acc1 = 0.f, acc2 = 0.f, acc3 = 0.f;
        float acc4 = 0.f, acc5 = 0.f, acc6 = 0.f, acc7 = 0.f;
        const uint4* ep = ell4 + r;

        // ---- 2-deep software pipeline over k-groups of 4 ----
        uint4 eA = ep[0];                           // group 0
        uint4 dA0, dA1, dA2, dA3;
        GATH(dA0, eA.x); GATH(dA1, eA.y); GATH(dA2, eA.z); GATH(dA3, eA.w);
        uint4 eB = ep[OUT_DIM];                     // group 1
        uint4 dB0, dB1, dB2, dB3;
        const uint4* epn = ep + 2 * (size_t)OUT_DIM;

        #pragma unroll 1
        for (int g = 0; g + 2 < ng; g += 2) {
            // step g: compute (eA,dA); gather g+1 from eB; prefetch e(g+2)
            const uint4 tA = epn[0];
            GATH(dB0, eB.x); GATH(dB1, eB.y); GATH(dB2, eB.z); GATH(dB3, eB.w);
            FMA8(eA.x, dA0); FMA8(eA.y, dA1); FMA8(eA.z, dA2); FMA8(eA.w, dA3);
            // step g+1: compute (eB,dB); gather g+2 from tA; prefetch e(g+3)
            const uint4 tB = epn[OUT_DIM];
            GATH(dA0, tA.x); GATH(dA1, tA.y); GATH(dA2, tA.z); GATH(dA3, tA.w);
            FMA8(eB.x, dB0); FMA8(eB.y, dB1); FMA8(eB.z, dB2); FMA8(eB.w, dB3);
            eA = tA; eB = tB;
            epn += 2 * (size_t)OUT_DIM;
        }
        // epilogue: last (odd) group already gathered in (eA, dA)
        FMA8(eA.x, dA0); FMA8(eA.y, dA1); FMA8(eA.z, dA2); FMA8(eA.w, dA3);

        __builtin_nontemporal_store(acc0, &y[(tb + 0) * OUT_DIM + r]);
        __builtin_nontemporal_store(acc1, &y[(tb + 1) * OUT_DIM + r]);
        __builtin_nontemporal_store(acc2, &y[(tb + 2) * OUT_DIM + r]);
        __builtin_nontemporal_store(acc3, &y[(tb + 3) * OUT_DIM + r]);
        __builtin_nontemporal_store(acc4, &y[(tb + 4) * OUT_DIM + r]);
        __builtin_nontemporal_store(acc5, &y[(tb + 5) * OUT_DIM + r]);
        __builtin_nontemporal_store(acc6, &y[(tb + 6) * OUT_DIM + r]);
        __builtin_nontemporal_store(acc7, &y[(tb + 7) * OUT_DIM + r]);
    }
}

// Fallback if d_ws too small for ELL: direct CSR (fp32 values, f16 tokens).
__global__ __launch_bounds__(TPB, 4)
void spmm_csr(const float* __restrict__ x, const float* __restrict__ values,
              const int* __restrict__ row_offs, const int* __restrict__ col_idx,
              float* __restrict__ y) {
    __shared__ __align__(16) uint32_t xs[IN_DIM * (TOKS / 2)];
    const int tid  = threadIdx.x;
    const size_t tb = (size_t)blockIdx.x * TOKS;

    stage_x_tile(x, tb, xs, tid);
    __syncthreads();

    #pragma unroll 1
    for (int chunk = 0; chunk < OUT_DIM / TPB; ++chunk) {
        const int r = chunk * TPB + tid;
        float acc0 = 0.f, acc1 = 0.f, acc2 = 0.f, acc3 = 0.f;
        float acc4 = 0.f, acc5 = 0.f, acc6 = 0.f, acc7 = 0.f;
        int k = row_offs[r];
        const int ke = row_offs[r + 1];
        for (; k < ke; ++k) {
            const uint32_t e = __float_as_uint(values[k]);
            const uint32_t off = (uint32_t)col_idx[k] << 4;
            uint4 d;
            GATH(d, off);
            FMA8(e, d);
        }
        y[(tb + 0) * OUT_DIM + r] = acc0;
        y[(tb + 1) * OUT_DIM + r] = acc1;
        y[(tb + 2) * OUT_DIM + r] = acc2;
        y[(tb + 3) * OUT_DIM + r] = acc3;
        y[(tb + 4) * OUT_DIM + r] = acc4;
        y[(tb + 5) * OUT_DIM + r] = acc5;
        y[(tb + 6) * OUT_DIM + r] = acc6;
        y[(tb + 7) * OUT_DIM + r] = acc7;
    }
}

extern "C" void kernel_launch(void* const* d_in, const int* in_sizes, int n_in,
                              void* d_out, int out_size, void* d_ws, size_t ws_size,
                              hipStream_t stream) {
    const float* x        = (const float*)d_in[0];
    const float* values   = (const float*)d_in[1];
    const int*   row_offs = (const int*)d_in[2];
    const int*   col_idx  = (const int*)d_in[3];
    float* y = (float*)d_out;

    const int nnz  = in_sizes[1];
    const int rows = in_sizes[2] - 1;              // 4096
    const int ntok = in_sizes[0] / IN_DIM;         // 8192
    const int kmax = nnz / rows + ((nnz % rows) ? 1 : 0);   // 41

    int ng = (kmax + 3) / 4;                       // k-groups of 4 (11 for kmax=41)
    if (!(ng & 1)) ++ng;                           // pipeline needs ODD ng
    const int galloc = ng + 1;                     // +1 zero group for e-prefetch

    dim3 grid(ntok / TOKS), block(TPB);
    const size_t ell_bytes = (size_t)galloc * OUT_DIM * sizeof(uint4);
    if (ws_size >= ell_bytes) {
        uint4* ell4 = (uint4*)d_ws;
        build_ell<<<dim3(OUT_DIM / BTPB), dim3(BTPB), 0, stream>>>(
            values, row_offs, col_idx, ell4, galloc);
        spmm_ell<<<grid, block, 0, stream>>>(x, ell4, y, ng);
    } else {
        spmm_csr<<<grid, block, 0, stream>>>(x, values, row_offs, col_idx, y);
    }
}

// Round 10
// 90.375 us; speedup vs baseline: 4.4614x; 1.2720x over previous
//
#include <hip/hip_runtime.h>
#include <hip/hip_fp16.h>
#include <stdint.h>

#define IN_DIM   4096
#define OUT_DIM  4096
#define TPB      1024     // 2 blocks/CU (128 KB LDS) = 32 waves/CU
#define NW       (TPB / 64)
#define TOKS     8        // tokens per block; LDS = 4 f16x2 pairs per column
#define BTPB     64       // build_ell threads per block (1 wave)
#define NSLOT    48       // max ELL slots per row handled by reorder

typedef float  f32x4 __attribute__((ext_vector_type(4)));

// pack two fp32 -> f16x2 dword (lo = a, hi = b) via v_cvt_pkrtz_f16_f32 (1 instr)
__device__ __forceinline__ uint32_t pack_f16x2(float a, float b) {
    auto h = __builtin_amdgcn_cvt_pkrtz(a, b);   // __fp16 ext_vector_type(2)
    uint32_t u;
    __builtin_memcpy(&u, &h, 4);
    return u;
}

// Stage 8 tokens of x (fp32, [token][IN_DIM]) into LDS as f16x2, column-major:
// xs[col*4 + pair]; pair p holds tokens (2p, 2p+1).
// Per-lane write rotation keeps staging writes ~2-way banked (free).
__device__ __forceinline__ void stage_x_tile(const float* __restrict__ x,
                                             size_t tb, uint32_t* xs, int tid) {
    const int lane = tid & 63;
    const int wave = tid >> 6;          // 0..NW-1
    const int tp   = lane >> 4;         // token pair 0..3
    const int rot  = (lane >> 1) & 3;   // write-order rotation
    const float* xa = x + (tb + 2 * (size_t)tp) * IN_DIM;
    const float* xb = xa + IN_DIM;
    #pragma unroll
    for (int it = 0; it < 64 / NW; ++it) {
        const int c4 = (lane & 15) + 16 * wave + (16 * NW) * it;  // float4 col group
        const f32x4 a = __builtin_nontemporal_load(
            reinterpret_cast<const f32x4*>(xa + 4 * c4));
        const f32x4 b = __builtin_nontemporal_load(
            reinterpret_cast<const f32x4*>(xb + 4 * c4));
        const uint32_t d0 = pack_f16x2(a[0], b[0]);
        const uint32_t d1 = pack_f16x2(a[1], b[1]);
        const uint32_t d2 = pack_f16x2(a[2], b[2]);
        const uint32_t d3 = pack_f16x2(a[3], b[3]);
        // branchless rotate-left by rot (no runtime array indexing -> no scratch)
        const uint32_t t0 = (rot & 2) ? d2 : d0;
        const uint32_t t1 = (rot & 2) ? d3 : d1;
        const uint32_t t2 = (rot & 2) ? d0 : d2;
        const uint32_t t3 = (rot & 2) ? d1 : d3;
        const uint32_t u0 = (rot & 1) ? t1 : t0;
        const uint32_t u1 = (rot & 1) ? t2 : t1;
        const uint32_t u2 = (rot & 1) ? t3 : t2;
        const uint32_t u3 = (rot & 1) ? t0 : t3;
        const int cb = 4 * c4;
        xs[(cb + ((0 + rot) & 3)) * 4 + tp] = u0;
        xs[(cb + ((1 + rot) & 3)) * 4 + tp] = u1;
        xs[(cb + ((2 + rot) & 3)) * 4 + tp] = u2;
        xs[(cb + ((3 + rot) & 3)) * 4 + tp] = u3;
    }
}

// ELL metadata, group-of-4 interleaved: ell4[g*OUT_DIM + r] = uint4 of entries
// k=4g..4g+3; entry = (f16(value) << 16) | (col << 4). Zero padded.
// BANK-AWARE SLOT ASSIGNMENT (O(k) counting sort): slot j prefers LDS bank
// quartet (j + r) & 7 (quartet of a 16B entry = col & 7) so 8 consecutive
// lanes tile the 8 quartets. One thread per row; scratch lane-interleaved in LDS.
__global__ __launch_bounds__(BTPB, 1)
void build_ell(const float* __restrict__ values,
               const int* __restrict__ row_offs,
               const int* __restrict__ col_idx,
               uint4* __restrict__ ell4, int galloc) {
    __shared__ uint32_t lA[NSLOT * BTPB];   // unsorted packed entries, 12 KB
    __shared__ uint32_t lB[NSLOT * BTPB];   // group-sorted packed entries, 12 KB
    const int tid = threadIdx.x;
    const int r = blockIdx.x * BTPB + tid;
    if (r >= OUT_DIM) return;
    const int beg = row_offs[r];
    const int end = row_offs[r + 1];
    int klen = end - beg;
    const int nslot = 4 * galloc > NSLOT ? NSLOT : 4 * galloc;
    if (klen > nslot) klen = nslot;   // safety (never hit: ELL sized from kmax)

    // pass 1: load + pack entries into lA; count per-group in cnt64 byte-fields
    uint64_t cnt64 = 0;
    for (int i = 0; i < klen; ++i) {
        const uint32_t c = (uint32_t)col_idx[beg + i];
        const uint32_t vh =
            (uint32_t)__half_as_ushort(__float2half(values[beg + i]));
        lA[i * BTPB + tid] = (vh << 16) | (c << 4);
        cnt64 += 1ull << (8 * (c & 7));
    }

    // pass 2: byte-field exclusive prefix sum -> off64; non-empty-group mask
    uint64_t off64 = 0;
    uint32_t mask = 0, run = 0;
    #pragma unroll
    for (int b = 0; b < 8; ++b) {
        off64 |= (uint64_t)run << (8 * b);
        const uint32_t cb = (uint32_t)(cnt64 >> (8 * b)) & 0xff;
        if (cb) mask |= 1u << b;
        run += cb;
    }

    // pass 3: stable counting sort by group into lB
    uint64_t cur64 = off64;
    for (int i = 0; i < klen; ++i) {
        const uint32_t u = lA[i * BTPB + tid];
        const int g = (u >> 4) & 7;
        const uint32_t pos = (uint32_t)(cur64 >> (8 * g)) & 0xff;
        cur64 += 1ull << (8 * g);
        lB[pos * BTPB + tid] = u;
    }

    // pass 4: emit slots; slot j takes first non-empty group clockwise from (j+r)&7
    uint64_t head64 = off64;
    uint64_t rem64  = cnt64;
    for (int g = 0; g < galloc; ++g) {
        uint32_t e0 = 0, e1 = 0, e2 = 0, e3 = 0;
        #pragma unroll
        for (int j4 = 0; j4 < 4; ++j4) {
            const int j = 4 * g + j4;
            uint32_t u = 0;
            if (j < klen) {
                const int t = (j + r) & 7;
                const uint32_t m2 = ((mask >> t) | (mask << (8 - t))) & 0xff;
                const int b = (t + __builtin_ctz(m2)) & 7;
                const uint32_t hb = (uint32_t)(head64 >> (8 * b)) & 0xff;
                u = lB[hb * BTPB + tid];
                head64 += 1ull << (8 * b);
                rem64  -= 1ull << (8 * b);
                if (!((rem64 >> (8 * b)) & 0xff)) mask &= ~(1u << b);
            }
            if (j4 == 0) e0 = u; else if (j4 == 1) e1 = u;
            else if (j4 == 2) e2 = u; else e3 = u;
        }
        ell4[(size_t)g * OUT_DIM + r] = make_uint4(e0, e1, e2, e3);
    }
}

// 8 MACs from one f16x2-packed uint4 (8 tokens) against value in E's hi-16.
// 4x v_pk_fma_f16, accumulate in packed f16 (error ~2e-4 over 41 terms).
#define FMA8(E, D)                                                   \
    do {                                                             \
        uint32_t t_ = (E) >> 16;                                     \
        t_ |= t_ << 16;                                              \
        __half2 vv_;                                                 \
        __builtin_memcpy(&vv_, &t_, 4);                              \
        const __half2* h_ = reinterpret_cast<const __half2*>(&(D));  \
        acc01 = __hfma2(vv_, h_[0], acc01);                          \
        acc23 = __hfma2(vv_, h_[1], acc23);                          \
        acc45 = __hfma2(vv_, h_[2], acc45);                          \
        acc67 = __hfma2(vv_, h_[3], acc67);                          \
    } while (0)

// gather: entry's low bits are already the byte offset (col<<4)
#define GATH(D, E)                                                           \
    (D) = *reinterpret_cast<const uint4*>(reinterpret_cast<const char*>(xs) + \
                                          ((E) & 0xfff0u))

__global__ __launch_bounds__(TPB, 8)
void spmm_ell(const float* __restrict__ x, const uint4* __restrict__ ell4,
              float* __restrict__ y, int ng) {   // ng is ODD
    __shared__ __align__(16) uint32_t xs[IN_DIM * (TOKS / 2)];   // 64 KB
    const int tid  = threadIdx.x;
    const size_t tb = (size_t)blockIdx.x * TOKS;

    stage_x_tile(x, tb, xs, tid);
    __syncthreads();

    #pragma unroll 1
    for (int chunk = 0; chunk < OUT_DIM / TPB; ++chunk) {
        const int r = chunk * TPB + tid;
        __half2 acc01 = __half2half2(__ushort_as_half(0));
        __half2 acc23 = acc01, acc45 = acc01, acc67 = acc01;
        const uint4* ep = ell4 + r;

        // ---- 2-deep software pipeline over k-groups of 4 ----
        uint4 eA = ep[0];                           // group 0
        uint4 dA0, dA1, dA2, dA3;
        GATH(dA0, eA.x); GATH(dA1, eA.y); GATH(dA2, eA.z); GATH(dA3, eA.w);
        uint4 eB = ep[OUT_DIM];                     // group 1
        uint4 dB0, dB1, dB2, dB3;
        const uint4* epn = ep + 2 * (size_t)OUT_DIM;

        #pragma unroll 1
        for (int g = 0; g + 2 < ng; g += 2) {
            // step g: compute (eA,dA); gather g+1 from eB; prefetch e(g+2)
            const uint4 tA = epn[0];
            GATH(dB0, eB.x); GATH(dB1, eB.y); GATH(dB2, eB.z); GATH(dB3, eB.w);
            FMA8(eA.x, dA0); FMA8(eA.y, dA1); FMA8(eA.z, dA2); FMA8(eA.w, dA3);
            // step g+1: compute (eB,dB); gather g+2 from tA; prefetch e(g+3)
            const uint4 tB = epn[OUT_DIM];
            GATH(dA0, tA.x); GATH(dA1, tA.y); GATH(dA2, tA.z); GATH(dA3, tA.w);
            FMA8(eB.x, dB0); FMA8(eB.y, dB1); FMA8(eB.z, dB2); FMA8(eB.w, dB3);
            eA = tA; eB = tB;
            epn += 2 * (size_t)OUT_DIM;
        }
        // epilogue: last (odd) group already gathered in (eA, dA)
        FMA8(eA.x, dA0); FMA8(eA.y, dA1); FMA8(eA.z, dA2); FMA8(eA.w, dA3);

        __builtin_nontemporal_store(__low2float(acc01),  &y[(tb + 0) * OUT_DIM + r]);
        __builtin_nontemporal_store(__high2float(acc01), &y[(tb + 1) * OUT_DIM + r]);
        __builtin_nontemporal_store(__low2float(acc23),  &y[(tb + 2) * OUT_DIM + r]);
        __builtin_nontemporal_store(__high2float(acc23), &y[(tb + 3) * OUT_DIM + r]);
        __builtin_nontemporal_store(__low2float(acc45),  &y[(tb + 4) * OUT_DIM + r]);
        __builtin_nontemporal_store(__high2float(acc45), &y[(tb + 5) * OUT_DIM + r]);
        __builtin_nontemporal_store(__low2float(acc67),  &y[(tb + 6) * OUT_DIM + r]);
        __builtin_nontemporal_store(__high2float(acc67), &y[(tb + 7) * OUT_DIM + r]);
    }
}

// Fallback if d_ws too small for ELL: direct CSR (fp32 values, f16 tokens).
__global__ __launch_bounds__(TPB, 8)
void spmm_csr(const float* __restrict__ x, const float* __restrict__ values,
              const int* __restrict__ row_offs, const int* __restrict__ col_idx,
              float* __restrict__ y) {
    __shared__ __align__(16) uint32_t xs[IN_DIM * (TOKS / 2)];
    const int tid  = threadIdx.x;
    const size_t tb = (size_t)blockIdx.x * TOKS;

    stage_x_tile(x, tb, xs, tid);
    __syncthreads();

    #pragma unroll 1
    for (int chunk = 0; chunk < OUT_DIM / TPB; ++chunk) {
        const int r = chunk * TPB + tid;
        __half2 acc01 = __half2half2(__ushort_as_half(0));
        __half2 acc23 = acc01, acc45 = acc01, acc67 = acc01;
        int k = row_offs[r];
        const int ke = row_offs[r + 1];
        for (; k < ke; ++k) {
            const uint32_t e =
            ((uint32_t)__half_as_ushort(__float2half(values[k])) << 16);
            const uint32_t off = ((uint32_t)col_idx[k] << 4) | e;
            uint4 d;
            GATH(d, off);
            FMA8(off, d);
        }
        y[(tb + 0) * OUT_DIM + r] = __low2float(acc01);
        y[(tb + 1) * OUT_DIM + r] = __high2float(acc01);
        y[(tb + 2) * OUT_DIM + r] = __low2float(acc23);
        y[(tb + 3) * OUT_DIM + r] = __high2float(acc23);
        y[(tb + 4) * OUT_DIM + r] = __low2float(acc45);
        y[(tb + 5) * OUT_DIM + r] = __high2float(acc45);
        y[(tb + 6) * OUT_DIM + r] = __low2float(acc67);
        y[(tb + 7) * OUT_DIM + r] = __high2float(acc67);
    }
}

extern "C" void kernel_launch(void* const* d_in, const int* in_sizes, int n_in,
                              void* d_out, int out_size, void* d_ws, size_t ws_size,
                              hipStream_t stream) {
    const float* x        = (const float*)d_in[0];
    const float* values   = (const float*)d_in[1];
    const int*   row_offs = (const int*)d_in[2];
    const int*   col_idx  = (const int*)d_in[3];
    float* y = (float*)d_out;

    const int nnz  = in_sizes[1];
    const int rows = in_sizes[2] - 1;              // 4096
    const int ntok = in_sizes[0] / IN_DIM;         // 8192
    const int kmax = nnz / rows + ((nnz % rows) ? 1 : 0);   // 41

    int ng = (kmax + 3) / 4;                       // k-groups of 4 (11 for kmax=41)
    if (!(ng & 1)) ++ng;                           // pipeline needs ODD ng
    const int galloc = ng + 1;                     // +1 zero group for e-prefetch

    dim3 grid(ntok / TOKS), block(TPB);
    const size_t ell_bytes = (size_t)galloc * OUT_DIM * sizeof(uint4);
    if (ws_size >= ell_bytes) {
        uint4* ell4 = (uint4*)d_ws;
        build_ell<<<dim3(OUT_DIM / BTPB), dim3(BTPB), 0, stream>>>(
            values, row_offs, col_idx, ell4, galloc);
        spmm_ell<<<grid, block, 0, stream>>>(x, ell4, y, ng);
    } else {
        spmm_csr<<<grid, block, 0, stream>>>(x, values, row_offs, col_idx, y);
    }
}